// Round 1
// 3095.236 us; speedup vs baseline: 3.0106x; 3.0106x over previous
//
#include <hip/hip_runtime.h>
#include <hip/hip_bf16.h>

// ---------------- problem constants ----------------
#define DMODEL 768
#define DINNER 1536
#define NROWS  4096      // B*L
#define SEQLEN 2048
#define DSTATE 16
#define DTRANK 48
#define DXP    80        // DTRANK + 2*DSTATE
#define NVOCAB 32000
#define TCHUNK 64
#define NCHUNK 32        // SEQLEN / TCHUNK

typedef unsigned short u16;
typedef __attribute__((ext_vector_type(8))) short  short8;
typedef __attribute__((ext_vector_type(4))) float  floatx4;

__device__ __forceinline__ u16 f2bf(float f) {
    unsigned u = __builtin_bit_cast(unsigned, f);
    unsigned r = 0x7FFFu + ((u >> 16) & 1u);   // RNE
    return (u16)((u + r) >> 16);
}
__device__ __forceinline__ float bf2f(u16 h) {
    unsigned u = ((unsigned)h) << 16;
    return __builtin_bit_cast(float, u);
}
__device__ __forceinline__ float siluf(float x) { return x / (1.f + expf(-x)); }
__device__ __forceinline__ float softplusf(float x) {
    return fmaxf(x, 0.f) + log1pf(__expf(-fabsf(x)));
}

// ---------------- split fp32 -> bf16 hi/lo ----------------
__global__ void k_split(const float* __restrict__ in, u16* __restrict__ hi,
                        u16* __restrict__ lo, int n4) {
    int i = blockIdx.x * blockDim.x + threadIdx.x;
    int stride = gridDim.x * blockDim.x;
    for (; i < n4; i += stride) {
        float4 f = ((const float4*)in)[i];
        u16 h0 = f2bf(f.x), h1 = f2bf(f.y), h2 = f2bf(f.z), h3 = f2bf(f.w);
        ushort4 hv; hv.x = h0; hv.y = h1; hv.z = h2; hv.w = h3;
        ((ushort4*)hi)[i] = hv;
        if (lo) {
            ushort4 lv;
            lv.x = f2bf(f.x - bf2f(h0));
            lv.y = f2bf(f.y - bf2f(h1));
            lv.z = f2bf(f.z - bf2f(h2));
            lv.w = f2bf(f.w - bf2f(h3));
            ((ushort4*)lo)[i] = lv;
        }
    }
}

// ---------------- embedding gather ----------------
__global__ void k_embed(const int* __restrict__ ids, const float* __restrict__ emb,
                        float* __restrict__ x) {
    int row = blockIdx.x;
    int id = ids[row];
    const float* src = emb + (size_t)id * DMODEL;
    float* dst = x + (size_t)row * DMODEL;
    for (int c = threadIdx.x; c < DMODEL; c += blockDim.x) dst[c] = src[c];
}

// ---------------- causal conv(k=4) + silu, plus silu(z) ----------------
__global__ void k_conv_silu(const float* __restrict__ xz, const float* __restrict__ cw,
                            const float* __restrict__ cb, float* __restrict__ ssm,
                            float* __restrict__ sz) {
    int row = blockIdx.y;                                  // 0..4095
    int d   = blockIdx.x * blockDim.x + threadIdx.x;       // 0..1535
    int t   = row & (SEQLEN - 1);
    float acc = cb[d];
    #pragma unroll
    for (int k = 0; k < 4; ++k) {
        int tt = t + k - 3;
        if (tt >= 0) acc += xz[(size_t)(row + k - 3) * (2 * DINNER) + d] * cw[d * 4 + k];
    }
    ssm[(size_t)row * DINNER + d] = siluf(acc);
    float z = xz[(size_t)row * (2 * DINNER) + DINNER + d];
    sz[(size_t)row * DINNER + d] = siluf(z);
}

// ---------------- softplus(dtp + b_dt) in place, vectorized ----------------
__global__ void k_softplus(float* __restrict__ dtp, const float* __restrict__ bd, int n4) {
    int i = blockIdx.x * blockDim.x + threadIdx.x;
    int stride = gridDim.x * blockDim.x;
    for (; i < n4; i += stride) {
        float4 v = ((float4*)dtp)[i];
        int d = (i * 4) % DINNER;                // DINNER % 4 == 0 -> stays in row
        float4 b = *(const float4*)&bd[d];
        v.x = softplusf(v.x + b.x);
        v.y = softplusf(v.y + b.y);
        v.z = softplusf(v.z + b.z);
        v.w = softplusf(v.w + b.w);
        ((float4*)dtp)[i] = v;
    }
}

// ---------------- chunked selective scan ----------------
// phase 1: per-chunk local scan (h0 = 0), record final h and P = prod(dA)
// grid: (NCHUNK, 2*96) ; block: 256 = 16 d x 16 s
__global__ void k_scan1(const float* __restrict__ dtp, const float* __restrict__ ssm,
                        const float* __restrict__ dbl, const float* __restrict__ Alog,
                        float* __restrict__ hend, float* __restrict__ Pout) {
    int ch   = blockIdx.x;
    int b    = blockIdx.y / (DINNER / 16);
    int dblk = blockIdx.y % (DINNER / 16);
    int dl = threadIdx.x >> 4;
    int s  = threadIdx.x & 15;
    int d  = dblk * 16 + dl;
    float A = -__expf(Alog[d * DSTATE + s]);
    float h = 0.f, P = 1.f;
    size_t row = (size_t)b * SEQLEN + (size_t)ch * TCHUNK;
    for (int t = 0; t < TCHUNK; ++t, ++row) {
        float dt = dtp[row * DINNER + d];
        float xv = ssm[row * DINNER + d];
        float Bv = dbl[row * DXP + DTRANK + s];
        float dA = __expf(dt * A);
        h = h * dA + dt * xv * Bv;
        P *= dA;
    }
    size_t o = (((size_t)b * NCHUNK + ch) * DINNER + d) * DSTATE + s;
    hend[o] = h;
    Pout[o] = P;
}

// phase 2: stitch chunk boundaries: h0[c+1] = hend[c] + P[c]*h0[c]
// grid: 192 x 256 ; thread = linear (b,d,s)
__global__ void k_scan2(const float* __restrict__ hend, const float* __restrict__ P,
                        float* __restrict__ h0) {
    int idx = blockIdx.x * blockDim.x + threadIdx.x;   // b*DINNER*DSTATE + d*DSTATE + s
    int b  = idx / (DINNER * DSTATE);
    int ds = idx % (DINNER * DSTATE);
    float h = 0.f;
    size_t base = (size_t)b * NCHUNK * DINNER * DSTATE + ds;
    for (int c = 0; c < NCHUNK; ++c) {
        size_t o = base + (size_t)c * (DINNER * DSTATE);
        h0[o] = h;
        h = hend[o] + P[o] * h;
    }
}

// phase 3: re-scan each chunk from correct h0, emit u
// grid: (NCHUNK, 2*96) ; block: 256 = 16 d x 16 s
__global__ void k_scan3(const float* __restrict__ dtp, const float* __restrict__ ssm,
                        const float* __restrict__ dbl, const float* __restrict__ Alog,
                        const float* __restrict__ Dpv, const float* __restrict__ sz,
                        const float* __restrict__ h0, float* __restrict__ u) {
    int ch   = blockIdx.x;
    int b    = blockIdx.y / (DINNER / 16);
    int dblk = blockIdx.y % (DINNER / 16);
    int dl = threadIdx.x >> 4;
    int s  = threadIdx.x & 15;
    int d  = dblk * 16 + dl;
    float A  = -__expf(Alog[d * DSTATE + s]);
    float Dd = Dpv[d];
    float h  = h0[(((size_t)b * NCHUNK + ch) * DINNER + d) * DSTATE + s];
    size_t row = (size_t)b * SEQLEN + (size_t)ch * TCHUNK;
    for (int t = 0; t < TCHUNK; ++t, ++row) {
        float dt = dtp[row * DINNER + d];
        float xv = ssm[row * DINNER + d];
        float Bv = dbl[row * DXP + DTRANK + s];
        float Cv = dbl[row * DXP + DTRANK + DSTATE + s];
        float dA = __expf(dt * A);
        h = h * dA + dt * xv * Bv;
        float yv = h * Cv;
        yv += __shfl_xor(yv, 1);
        yv += __shfl_xor(yv, 2);
        yv += __shfl_xor(yv, 4);
        yv += __shfl_xor(yv, 8);
        if (s == 0) u[row * DINNER + d] = (yv + xv * Dd) * sz[row * DINNER + d];
    }
}

// ---------------- LayerNorm -> bf16 ----------------
__global__ void k_ln(const float* __restrict__ x, const float* __restrict__ g,
                     const float* __restrict__ bb, u16* __restrict__ out) {
    __shared__ float red[256];
    int row = blockIdx.x;
    int tid = threadIdx.x;
    const float* xr = x + (size_t)row * DMODEL;
    float v0 = xr[tid], v1 = xr[tid + 256], v2 = xr[tid + 512];
    red[tid] = v0 + v1 + v2;
    __syncthreads();
    for (int o = 128; o > 0; o >>= 1) { if (tid < o) red[tid] += red[tid + o]; __syncthreads(); }
    float mu = red[0] * (1.f / 768.f);
    __syncthreads();
    red[tid] = (v0 - mu) * (v0 - mu) + (v1 - mu) * (v1 - mu) + (v2 - mu) * (v2 - mu);
    __syncthreads();
    for (int o = 128; o > 0; o >>= 1) { if (tid < o) red[tid] += red[tid + o]; __syncthreads(); }
    float var = red[0] * (1.f / 768.f);
    float rs = rsqrtf(var + 1e-5f);
    u16* orow = out + (size_t)row * DMODEL;
    orow[tid]       = f2bf((v0 - mu) * rs * g[tid]       + bb[tid]);
    orow[tid + 256] = f2bf((v1 - mu) * rs * g[tid + 256] + bb[tid + 256]);
    orow[tid + 512] = f2bf((v2 - mu) * rs * g[tid + 512] + bb[tid + 512]);
}

// ---------------- generic MFMA GEMM: C[M][N] = A[M][K] * B[N][K]^T ----------------
// SPLIT=1: fp32-accurate via bf16 hi/lo (Ah*Bh + Al*Bh + Ah*Bl)
template<int SPLIT>
__global__ __launch_bounds__(256, 2)
void k_gemm(const u16* __restrict__ Ah, const u16* __restrict__ Al,
            const u16* __restrict__ Bh, const u16* __restrict__ Bl,
            float* __restrict__ C, int M, int N, int K, int lda, int ldb, int ldc) {
    constexpr int LDK = 40;                       // 32 + 8 pad (80B row stride)
    __shared__ __align__(16) u16 sA[2][128 * LDK];
    __shared__ __align__(16) u16 sB[2][128 * LDK];
    const int tid  = threadIdx.x;
    const int m0 = blockIdx.y * 128, n0 = blockIdx.x * 128;
    const int wave = tid >> 6, lane = tid & 63;
    const int wm = (wave >> 1) * 64, wn = (wave & 1) * 64;
    const int fr = lane & 15, fq = lane >> 4;

    floatx4 acc[4][4];
    #pragma unroll
    for (int i = 0; i < 4; ++i)
        #pragma unroll
        for (int j = 0; j < 4; ++j)
            #pragma unroll
            for (int r = 0; r < 4; ++r) acc[i][j][r] = 0.f;

    for (int kt = 0; kt < K; kt += 32) {
        __syncthreads();
        #pragma unroll
        for (int half = 0; half < 2; ++half) {
            int c  = tid + half * 256;       // 0..511
            int rr = c >> 2;                 // tile row 0..127
            int ko = (c & 3) * 8;            // k offset in tile
            int gk = kt + ko;
            {   // A tile(s)
                int gm = m0 + rr;
                short8 vh = {0,0,0,0,0,0,0,0}, vl = {0,0,0,0,0,0,0,0};
                if (gm < M) {
                    const u16* p = Ah + (size_t)gm * lda + gk;
                    if (gk + 8 <= K) vh = *(const short8*)p;
                    else { for (int jj = 0; jj < 8; ++jj) if (gk + jj < K) vh[jj] = (short)p[jj]; }
                    if (SPLIT) {
                        const u16* q = Al + (size_t)gm * lda + gk;
                        if (gk + 8 <= K) vl = *(const short8*)q;
                        else { for (int jj = 0; jj < 8; ++jj) if (gk + jj < K) vl[jj] = (short)q[jj]; }
                    }
                }
                *(short8*)&sA[0][rr * LDK + ko] = vh;
                if (SPLIT) *(short8*)&sA[1][rr * LDK + ko] = vl;
            }
            {   // B tile(s)
                int gn = n0 + rr;
                short8 vh = {0,0,0,0,0,0,0,0}, vl = {0,0,0,0,0,0,0,0};
                if (gn < N) {
                    const u16* p = Bh + (size_t)gn * ldb + gk;
                    if (gk + 8 <= K) vh = *(const short8*)p;
                    else { for (int jj = 0; jj < 8; ++jj) if (gk + jj < K) vh[jj] = (short)p[jj]; }
                    if (SPLIT) {
                        const u16* q = Bl + (size_t)gn * ldb + gk;
                        if (gk + 8 <= K) vl = *(const short8*)q;
                        else { for (int jj = 0; jj < 8; ++jj) if (gk + jj < K) vl[jj] = (short)q[jj]; }
                    }
                }
                *(short8*)&sB[0][rr * LDK + ko] = vh;
                if (SPLIT) *(short8*)&sB[1][rr * LDK + ko] = vl;
            }
        }
        __syncthreads();

        short8 aH[4], bH[4];
        #pragma unroll
        for (int i = 0; i < 4; ++i) aH[i] = *(const short8*)&sA[0][(wm + i * 16 + fr) * LDK + fq * 8];
        #pragma unroll
        for (int j = 0; j < 4; ++j) bH[j] = *(const short8*)&sB[0][(wn + j * 16 + fr) * LDK + fq * 8];
        #pragma unroll
        for (int i = 0; i < 4; ++i)
            #pragma unroll
            for (int j = 0; j < 4; ++j)
                acc[i][j] = __builtin_amdgcn_mfma_f32_16x16x32_bf16(aH[i], bH[j], acc[i][j], 0, 0, 0);
        if (SPLIT) {
            short8 aL[4], bL[4];
            #pragma unroll
            for (int i = 0; i < 4; ++i) aL[i] = *(const short8*)&sA[1][(wm + i * 16 + fr) * LDK + fq * 8];
            #pragma unroll
            for (int j = 0; j < 4; ++j) bL[j] = *(const short8*)&sB[1][(wn + j * 16 + fr) * LDK + fq * 8];
            #pragma unroll
            for (int i = 0; i < 4; ++i)
                #pragma unroll
                for (int j = 0; j < 4; ++j) {
                    acc[i][j] = __builtin_amdgcn_mfma_f32_16x16x32_bf16(aL[i], bH[j], acc[i][j], 0, 0, 0);
                    acc[i][j] = __builtin_amdgcn_mfma_f32_16x16x32_bf16(aH[i], bL[j], acc[i][j], 0, 0, 0);
                }
        }
    }
    // C/D layout (verified m89/m91): col = lane&15, row = (lane>>4)*4 + reg
    #pragma unroll
    for (int i = 0; i < 4; ++i)
        #pragma unroll
        for (int j = 0; j < 4; ++j) {
            int m = m0 + wm + i * 16 + fq * 4;
            int n = n0 + wn + j * 16 + fr;
            if (n < N) {
                #pragma unroll
                for (int r = 0; r < 4; ++r)
                    if (m + r < M) C[(size_t)(m + r) * ldc + n] = acc[i][j][r];
            }
        }
}

// ---------------- launch ----------------
extern "C" void kernel_launch(void* const* d_in, const int* in_sizes, int n_in,
                              void* d_out, int out_size, void* d_ws, size_t ws_size,
                              hipStream_t stream) {
    const int*   ids   = (const int*)d_in[0];
    const float* emb   = (const float*)d_in[1];
    const float* W_in  = (const float*)d_in[2];
    const float* cw    = (const float*)d_in[3];
    const float* cb    = (const float*)d_in[4];
    const float* W_x   = (const float*)d_in[5];
    const float* W_dt  = (const float*)d_in[6];
    const float* b_dt  = (const float*)d_in[7];
    const float* Alog  = (const float*)d_in[8];
    const float* Dp    = (const float*)d_in[9];
    const float* W_out = (const float*)d_in[10];
    const float* ln_g  = (const float*)d_in[11];
    const float* ln_b  = (const float*)d_in[12];
    const float* W_hd  = (const float*)d_in[13];

    char* ws = (char*)d_ws;
    float* xb   = (float*)(ws + 0);            // 4096x768   f32
    float* xz   = (float*)(ws + 12582912);     // 4096x3072  f32 (reused: dtp, u, head bf16)
    float* ssm  = (float*)(ws + 62914560);     // 4096x1536  f32
    float* szb  = (float*)(ws + 88080384);     // 4096x1536  f32
    float* dbl  = (float*)(ws + 113246208);    // 4096x80    f32
    u16*   Ahb  = (u16*)(ws + 114556928);      // 4096x1536  bf16
    u16*   Alb  = (u16*)(ws + 127139840);
    u16*   Bhb  = (u16*)(ws + 139722752);      // 3072x768   bf16
    u16*   Blb  = (u16*)(ws + 144441344);
    u16*   dblh = (u16*)(ws + 149159936);      // 4096x80    bf16
    u16*   dbll = (u16*)(ws + 149815296);      // total 150,470,656 B

    float* dtp = xz;                           // xz region dead after conv
    float* ub  = xz + (size_t)NROWS * DINNER;
    u16*   lnh = Ahb;                          // reuse after last layer
    u16*   hdh = (u16*)xz;                     // 32000x768 bf16 = 49.15MB <= xz region

    // scan scratch: Ahb/Alb/Bhb regions are dead between dt_proj gemm and out_proj split
    float* hendb = (float*)Ahb;                // 2*32*1536*16 f32 = 6,291,456 B (fits 12.58MB)
    float* Pb    = (float*)Alb;                // 6,291,456 B (fits 12.58MB)
    float* h0b   = (float*)Bhb;                // 6,291,456 B (fits Bhb+Blb = 9.44MB)

    k_embed<<<NROWS, 256, 0, stream>>>(ids, emb, xb);

    for (int i = 0; i < 4; ++i) {
        // in_proj: xz = x @ W_in^T   (M=4096,N=3072,K=768)
        k_split<<<2048, 256, 0, stream>>>(xb, Ahb, Alb, NROWS * DMODEL / 4);
        k_split<<<2048, 256, 0, stream>>>(W_in + (size_t)i * 3072 * DMODEL, Bhb, Blb, 3072 * DMODEL / 4);
        k_gemm<1><<<dim3(24, 32), 256, 0, stream>>>(Ahb, Alb, Bhb, Blb, xz,
                                                    NROWS, 3072, DMODEL, DMODEL, DMODEL, 3072);
        // conv + silu, silu(z)
        k_conv_silu<<<dim3(6, NROWS), 256, 0, stream>>>(xz, cw + (size_t)i * DINNER * 4,
                                                        cb + (size_t)i * DINNER, ssm, szb);
        // x_proj: dbl = ssm @ W_x^T  (N=80,K=1536)
        k_split<<<2048, 256, 0, stream>>>(ssm, Ahb, Alb, NROWS * DINNER / 4);
        k_split<<<480, 256, 0, stream>>>(W_x + (size_t)i * DXP * DINNER, Bhb, Blb, DXP * DINNER / 4);
        k_gemm<1><<<dim3(1, 32), 256, 0, stream>>>(Ahb, Alb, Bhb, Blb, dbl,
                                                   NROWS, DXP, DINNER, DINNER, DINNER, DXP);
        // dt_proj: dtp = dbl[:, :48] @ W_dt^T  (N=1536,K=48, lda=80)
        k_split<<<320, 256, 0, stream>>>(dbl, dblh, dbll, NROWS * DXP / 4);
        k_split<<<72, 256, 0, stream>>>(W_dt + (size_t)i * DINNER * DTRANK, Bhb, Blb, DINNER * DTRANK / 4);
        k_gemm<1><<<dim3(12, 32), 256, 0, stream>>>(dblh, dbll, Bhb, Blb, dtp,
                                                    NROWS, DINNER, DTRANK, DXP, DTRANK, DINNER);
        // selective scan, chunk-parallel:
        // softplus(dtp + b_dt) in place (was recomputed x16 lanes x 2048 steps inside scan)
        k_softplus<<<2048, 256, 0, stream>>>(dtp, b_dt + (size_t)i * DINNER, NROWS * DINNER / 4);
        // phase 1: per-chunk local scan (h0=0), record hend + P
        k_scan1<<<dim3(NCHUNK, 2 * (DINNER / 16)), 256, 0, stream>>>(
            dtp, ssm, dbl, Alog + (size_t)i * DINNER * DSTATE, hendb, Pb);
        // phase 2: stitch chunk boundaries (tiny)
        k_scan2<<<192, 256, 0, stream>>>(hendb, Pb, h0b);
        // phase 3: re-scan from correct h0, emit u (+D skip, *silu(z))
        k_scan3<<<dim3(NCHUNK, 2 * (DINNER / 16)), 256, 0, stream>>>(
            dtp, ssm, dbl, Alog + (size_t)i * DINNER * DSTATE,
            Dp + (size_t)i * DINNER, szb, h0b, ub);
        // out_proj: x = u @ W_out^T  (N=768,K=1536)
        k_split<<<2048, 256, 0, stream>>>(ub, Ahb, Alb, NROWS * DINNER / 4);
        k_split<<<2048, 256, 0, stream>>>(W_out + (size_t)i * DMODEL * DINNER, Bhb, Blb, DMODEL * DINNER / 4);
        k_gemm<1><<<dim3(6, 32), 256, 0, stream>>>(Ahb, Alb, Bhb, Blb, xb,
                                                   NROWS, DMODEL, DINNER, DINNER, DINNER, DMODEL);
    }

    k_ln<<<NROWS, 256, 0, stream>>>(xb, ln_g, ln_b, lnh);
    k_split<<<8192, 256, 0, stream>>>(W_hd, hdh, (u16*)nullptr, NVOCAB * DMODEL / 4);
    // head: logits = ln(x) @ W_head^T  (plain bf16 — error ~0.16% of max << 2% bar)
    k_gemm<0><<<dim3(250, 32), 256, 0, stream>>>(lnh, nullptr, hdh, nullptr, (float*)d_out,
                                                 NROWS, NVOCAB, DMODEL, DMODEL, DMODEL, NVOCAB);
}

// Round 2
// 2914.500 us; speedup vs baseline: 3.1973x; 1.0620x over previous
//
#include <hip/hip_runtime.h>
#include <hip/hip_bf16.h>

// ---------------- problem constants ----------------
#define DMODEL 768
#define DINNER 1536
#define NROWS  4096      // B*L
#define SEQLEN 2048
#define DSTATE 16
#define DTRANK 48
#define DXP    80        // DTRANK + 2*DSTATE
#define NVOCAB 32000
#define TCHUNK 64
#define NCHUNK 32        // SEQLEN / TCHUNK

typedef unsigned short u16;
typedef __attribute__((ext_vector_type(8))) short  short8;
typedef __attribute__((ext_vector_type(4))) float  floatx4;

__device__ __forceinline__ u16 f2bf(float f) {
    unsigned u = __builtin_bit_cast(unsigned, f);
    unsigned r = 0x7FFFu + ((u >> 16) & 1u);   // RNE
    return (u16)((u + r) >> 16);
}
__device__ __forceinline__ float bf2f(u16 h) {
    unsigned u = ((unsigned)h) << 16;
    return __builtin_bit_cast(float, u);
}
__device__ __forceinline__ float siluf(float x) { return x / (1.f + expf(-x)); }
__device__ __forceinline__ float softplusf(float x) {
    return fmaxf(x, 0.f) + log1pf(__expf(-fabsf(x)));
}
// async global -> LDS, 16B per lane; l must be wave-uniform
__device__ __forceinline__ void gload_lds16(const u16* g, u16* l) {
    __builtin_amdgcn_global_load_lds((const __attribute__((address_space(1))) void*)g,
                                     (__attribute__((address_space(3))) void*)l, 16, 0, 0);
}

// ---------------- split fp32 -> bf16 hi/lo ----------------
__global__ void k_split(const float* __restrict__ in, u16* __restrict__ hi,
                        u16* __restrict__ lo, int n4) {
    int i = blockIdx.x * blockDim.x + threadIdx.x;
    int stride = gridDim.x * blockDim.x;
    for (; i < n4; i += stride) {
        float4 f = ((const float4*)in)[i];
        u16 h0 = f2bf(f.x), h1 = f2bf(f.y), h2 = f2bf(f.z), h3 = f2bf(f.w);
        ushort4 hv; hv.x = h0; hv.y = h1; hv.z = h2; hv.w = h3;
        ((ushort4*)hi)[i] = hv;
        if (lo) {
            ushort4 lv;
            lv.x = f2bf(f.x - bf2f(h0));
            lv.y = f2bf(f.y - bf2f(h1));
            lv.z = f2bf(f.z - bf2f(h2));
            lv.w = f2bf(f.w - bf2f(h3));
            ((ushort4*)lo)[i] = lv;
        }
    }
}

// ---------------- embedding gather ----------------
__global__ void k_embed(const int* __restrict__ ids, const float* __restrict__ emb,
                        float* __restrict__ x) {
    int row = blockIdx.x;
    int id = ids[row];
    const float* src = emb + (size_t)id * DMODEL;
    float* dst = x + (size_t)row * DMODEL;
    for (int c = threadIdx.x; c < DMODEL; c += blockDim.x) dst[c] = src[c];
}

// ---------------- causal conv(k=4) + silu, plus silu(z) ----------------
__global__ void k_conv_silu(const float* __restrict__ xz, const float* __restrict__ cw,
                            const float* __restrict__ cb, float* __restrict__ ssm,
                            float* __restrict__ sz) {
    int row = blockIdx.y;                                  // 0..4095
    int d   = blockIdx.x * blockDim.x + threadIdx.x;       // 0..1535
    int t   = row & (SEQLEN - 1);
    float acc = cb[d];
    #pragma unroll
    for (int k = 0; k < 4; ++k) {
        int tt = t + k - 3;
        if (tt >= 0) acc += xz[(size_t)(row + k - 3) * (2 * DINNER) + d] * cw[d * 4 + k];
    }
    ssm[(size_t)row * DINNER + d] = siluf(acc);
    float z = xz[(size_t)row * (2 * DINNER) + DINNER + d];
    sz[(size_t)row * DINNER + d] = siluf(z);
}

// ---------------- softplus(dtp + b_dt) in place, vectorized ----------------
__global__ void k_softplus(float* __restrict__ dtp, const float* __restrict__ bd, int n4) {
    int i = blockIdx.x * blockDim.x + threadIdx.x;
    int stride = gridDim.x * blockDim.x;
    for (; i < n4; i += stride) {
        float4 v = ((float4*)dtp)[i];
        int d = (i * 4) % DINNER;                // DINNER % 4 == 0 -> stays in row
        float4 b = *(const float4*)&bd[d];
        v.x = softplusf(v.x + b.x);
        v.y = softplusf(v.y + b.y);
        v.z = softplusf(v.z + b.z);
        v.w = softplusf(v.w + b.w);
        ((float4*)dtp)[i] = v;
    }
}

// ---------------- chunked selective scan ----------------
// phase 1: per-chunk local scan (h0 = 0), record final h and P = prod(dA)
__global__ void k_scan1(const float* __restrict__ dtp, const float* __restrict__ ssm,
                        const float* __restrict__ dbl, const float* __restrict__ Alog,
                        float* __restrict__ hend, float* __restrict__ Pout) {
    int ch   = blockIdx.x;
    int b    = blockIdx.y / (DINNER / 16);
    int dblk = blockIdx.y % (DINNER / 16);
    int dl = threadIdx.x >> 4;
    int s  = threadIdx.x & 15;
    int d  = dblk * 16 + dl;
    float A = -__expf(Alog[d * DSTATE + s]);
    float h = 0.f, P = 1.f;
    size_t row = (size_t)b * SEQLEN + (size_t)ch * TCHUNK;
    for (int t = 0; t < TCHUNK; ++t, ++row) {
        float dt = dtp[row * DINNER + d];
        float xv = ssm[row * DINNER + d];
        float Bv = dbl[row * DXP + DTRANK + s];
        float dA = __expf(dt * A);
        h = h * dA + dt * xv * Bv;
        P *= dA;
    }
    size_t o = (((size_t)b * NCHUNK + ch) * DINNER + d) * DSTATE + s;
    hend[o] = h;
    Pout[o] = P;
}

// phase 2: stitch chunk boundaries: h0[c+1] = hend[c] + P[c]*h0[c]
__global__ void k_scan2(const float* __restrict__ hend, const float* __restrict__ P,
                        float* __restrict__ h0) {
    int idx = blockIdx.x * blockDim.x + threadIdx.x;   // b*DINNER*DSTATE + d*DSTATE + s
    int b  = idx / (DINNER * DSTATE);
    int ds = idx % (DINNER * DSTATE);
    float h = 0.f;
    size_t base = (size_t)b * NCHUNK * DINNER * DSTATE + ds;
    for (int c = 0; c < NCHUNK; ++c) {
        size_t o = base + (size_t)c * (DINNER * DSTATE);
        h0[o] = h;
        h = hend[o] + P[o] * h;
    }
}

// phase 3: re-scan each chunk from correct h0, emit u
__global__ void k_scan3(const float* __restrict__ dtp, const float* __restrict__ ssm,
                        const float* __restrict__ dbl, const float* __restrict__ Alog,
                        const float* __restrict__ Dpv, const float* __restrict__ sz,
                        const float* __restrict__ h0, float* __restrict__ u) {
    int ch   = blockIdx.x;
    int b    = blockIdx.y / (DINNER / 16);
    int dblk = blockIdx.y % (DINNER / 16);
    int dl = threadIdx.x >> 4;
    int s  = threadIdx.x & 15;
    int d  = dblk * 16 + dl;
    float A  = -__expf(Alog[d * DSTATE + s]);
    float Dd = Dpv[d];
    float h  = h0[(((size_t)b * NCHUNK + ch) * DINNER + d) * DSTATE + s];
    size_t row = (size_t)b * SEQLEN + (size_t)ch * TCHUNK;
    for (int t = 0; t < TCHUNK; ++t, ++row) {
        float dt = dtp[row * DINNER + d];
        float xv = ssm[row * DINNER + d];
        float Bv = dbl[row * DXP + DTRANK + s];
        float Cv = dbl[row * DXP + DTRANK + DSTATE + s];
        float dA = __expf(dt * A);
        h = h * dA + dt * xv * Bv;
        float yv = h * Cv;
        yv += __shfl_xor(yv, 1);
        yv += __shfl_xor(yv, 2);
        yv += __shfl_xor(yv, 4);
        yv += __shfl_xor(yv, 8);
        if (s == 0) u[row * DINNER + d] = (yv + xv * Dd) * sz[row * DINNER + d];
    }
}

// ---------------- LayerNorm -> bf16 ----------------
__global__ void k_ln(const float* __restrict__ x, const float* __restrict__ g,
                     const float* __restrict__ bb, u16* __restrict__ out) {
    __shared__ float red[256];
    int row = blockIdx.x;
    int tid = threadIdx.x;
    const float* xr = x + (size_t)row * DMODEL;
    float v0 = xr[tid], v1 = xr[tid + 256], v2 = xr[tid + 512];
    red[tid] = v0 + v1 + v2;
    __syncthreads();
    for (int o = 128; o > 0; o >>= 1) { if (tid < o) red[tid] += red[tid + o]; __syncthreads(); }
    float mu = red[0] * (1.f / 768.f);
    __syncthreads();
    red[tid] = (v0 - mu) * (v0 - mu) + (v1 - mu) * (v1 - mu) + (v2 - mu) * (v2 - mu);
    __syncthreads();
    for (int o = 128; o > 0; o >>= 1) { if (tid < o) red[tid] += red[tid + o]; __syncthreads(); }
    float var = red[0] * (1.f / 768.f);
    float rs = rsqrtf(var + 1e-5f);
    u16* orow = out + (size_t)row * DMODEL;
    orow[tid]       = f2bf((v0 - mu) * rs * g[tid]       + bb[tid]);
    orow[tid + 256] = f2bf((v1 - mu) * rs * g[tid + 256] + bb[tid + 256]);
    orow[tid + 512] = f2bf((v2 - mu) * rs * g[tid + 512] + bb[tid + 512]);
}

// ---------------- generic MFMA GEMM (bounds-checked): C = A[M][K] * B[N][K]^T ----------------
template<int SPLIT>
__global__ __launch_bounds__(256, 2)
void k_gemm(const u16* __restrict__ Ah, const u16* __restrict__ Al,
            const u16* __restrict__ Bh, const u16* __restrict__ Bl,
            float* __restrict__ C, int M, int N, int K, int lda, int ldb, int ldc) {
    constexpr int LDK = 40;                       // 32 + 8 pad (80B row stride)
    __shared__ __align__(16) u16 sA[2][128 * LDK];
    __shared__ __align__(16) u16 sB[2][128 * LDK];
    const int tid  = threadIdx.x;
    const int m0 = blockIdx.y * 128, n0 = blockIdx.x * 128;
    const int wave = tid >> 6, lane = tid & 63;
    const int wm = (wave >> 1) * 64, wn = (wave & 1) * 64;
    const int fr = lane & 15, fq = lane >> 4;

    floatx4 acc[4][4];
    #pragma unroll
    for (int i = 0; i < 4; ++i)
        #pragma unroll
        for (int j = 0; j < 4; ++j)
            #pragma unroll
            for (int r = 0; r < 4; ++r) acc[i][j][r] = 0.f;

    for (int kt = 0; kt < K; kt += 32) {
        __syncthreads();
        #pragma unroll
        for (int half = 0; half < 2; ++half) {
            int c  = tid + half * 256;       // 0..511
            int rr = c >> 2;                 // tile row 0..127
            int ko = (c & 3) * 8;            // k offset in tile
            int gk = kt + ko;
            {   // A tile(s)
                int gm = m0 + rr;
                short8 vh = {0,0,0,0,0,0,0,0}, vl = {0,0,0,0,0,0,0,0};
                if (gm < M) {
                    const u16* p = Ah + (size_t)gm * lda + gk;
                    if (gk + 8 <= K) vh = *(const short8*)p;
                    else { for (int jj = 0; jj < 8; ++jj) if (gk + jj < K) vh[jj] = (short)p[jj]; }
                    if (SPLIT) {
                        const u16* q = Al + (size_t)gm * lda + gk;
                        if (gk + 8 <= K) vl = *(const short8*)q;
                        else { for (int jj = 0; jj < 8; ++jj) if (gk + jj < K) vl[jj] = (short)q[jj]; }
                    }
                }
                *(short8*)&sA[0][rr * LDK + ko] = vh;
                if (SPLIT) *(short8*)&sA[1][rr * LDK + ko] = vl;
            }
            {   // B tile(s)
                int gn = n0 + rr;
                short8 vh = {0,0,0,0,0,0,0,0}, vl = {0,0,0,0,0,0,0,0};
                if (gn < N) {
                    const u16* p = Bh + (size_t)gn * ldb + gk;
                    if (gk + 8 <= K) vh = *(const short8*)p;
                    else { for (int jj = 0; jj < 8; ++jj) if (gk + jj < K) vh[jj] = (short)p[jj]; }
                    if (SPLIT) {
                        const u16* q = Bl + (size_t)gn * ldb + gk;
                        if (gk + 8 <= K) vl = *(const short8*)q;
                        else { for (int jj = 0; jj < 8; ++jj) if (gk + jj < K) vl[jj] = (short)q[jj]; }
                    }
                }
                *(short8*)&sB[0][rr * LDK + ko] = vh;
                if (SPLIT) *(short8*)&sB[1][rr * LDK + ko] = vl;
            }
        }
        __syncthreads();

        short8 aH[4], bH[4];
        #pragma unroll
        for (int i = 0; i < 4; ++i) aH[i] = *(const short8*)&sA[0][(wm + i * 16 + fr) * LDK + fq * 8];
        #pragma unroll
        for (int j = 0; j < 4; ++j) bH[j] = *(const short8*)&sB[0][(wn + j * 16 + fr) * LDK + fq * 8];
        #pragma unroll
        for (int i = 0; i < 4; ++i)
            #pragma unroll
            for (int j = 0; j < 4; ++j)
                acc[i][j] = __builtin_amdgcn_mfma_f32_16x16x32_bf16(aH[i], bH[j], acc[i][j], 0, 0, 0);
        if (SPLIT) {
            short8 aL[4], bL[4];
            #pragma unroll
            for (int i = 0; i < 4; ++i) aL[i] = *(const short8*)&sA[1][(wm + i * 16 + fr) * LDK + fq * 8];
            #pragma unroll
            for (int j = 0; j < 4; ++j) bL[j] = *(const short8*)&sB[1][(wn + j * 16 + fr) * LDK + fq * 8];
            #pragma unroll
            for (int i = 0; i < 4; ++i)
                #pragma unroll
                for (int j = 0; j < 4; ++j) {
                    acc[i][j] = __builtin_amdgcn_mfma_f32_16x16x32_bf16(aL[i], bH[j], acc[i][j], 0, 0, 0);
                    acc[i][j] = __builtin_amdgcn_mfma_f32_16x16x32_bf16(aH[i], bL[j], acc[i][j], 0, 0, 0);
                }
        }
    }
    // C/D layout (verified m89/m91): col = lane&15, row = (lane>>4)*4 + reg
    #pragma unroll
    for (int i = 0; i < 4; ++i)
        #pragma unroll
        for (int j = 0; j < 4; ++j) {
            int m = m0 + wm + i * 16 + fq * 4;
            int n = n0 + wn + j * 16 + fr;
            if (n < N) {
                #pragma unroll
                for (int r = 0; r < 4; ++r)
                    if (m + r < M) C[(size_t)(m + r) * ldc + n] = acc[i][j][r];
            }
        }
}

// ---------------- fast MFMA GEMM: requires M%128==0, N%128==0, K%32==0 ----------------
// global_load_lds staging (linear LDS dest, pre-swizzled global source, swizzled read)
// slot swizzle: physical 16B slot p of row r holds logical slot p^(r&3)  (4-way vs 8-way conflict)
template<int SPLIT>
__global__ __launch_bounds__(256, 2)
void k_gemm_fast(const u16* __restrict__ Ah, const u16* __restrict__ Al,
                 const u16* __restrict__ Bh, const u16* __restrict__ Bl,
                 float* __restrict__ C, int lda, int ldb, int ldc, int K) {
    __shared__ __align__(16) u16 sA[SPLIT + 1][128 * 32];
    __shared__ __align__(16) u16 sB[SPLIT + 1][128 * 32];
    // bijective XCD swizzle (m204)
    const int nx = gridDim.x;
    const int nwg = nx * gridDim.y;
    const int lin = blockIdx.y * nx + blockIdx.x;
    const int qq = nwg >> 3, rr8 = nwg & 7;
    const int xcd = lin & 7, jj = lin >> 3;
    const int swz = (xcd < rr8 ? xcd * (qq + 1) : rr8 * (qq + 1) + (xcd - rr8) * qq) + jj;
    const int n0 = (swz % nx) * 128, m0 = (swz / nx) * 128;

    const int tid  = threadIdx.x;
    const int wave = tid >> 6, lane = tid & 63;
    const int wm = (wave >> 1) * 64, wn = (wave & 1) * 64;
    const int fr = lane & 15, fq = lane >> 4;

    // staging geometry: wave covers rows [wave*32, wave*32+32) in two 1KB issues
    const int srow = (wave << 5) + (lane >> 2);                   // row for qi=0
    const int scol = (((lane & 3) ^ ((lane >> 2) & 3)) << 3);     // pre-swizzled u16 col
    const int ldsoff0 = (wave << 5) * 32;                         // wave-uniform

    floatx4 acc[4][4];
    #pragma unroll
    for (int i = 0; i < 4; ++i)
        #pragma unroll
        for (int j = 0; j < 4; ++j)
            #pragma unroll
            for (int r = 0; r < 4; ++r) acc[i][j][r] = 0.f;

    for (int kt = 0; kt < K; kt += 32) {
        __syncthreads();
        #pragma unroll
        for (int qi = 0; qi < 2; ++qi) {
            const int row = srow + qi * 16;
            const int lo  = ldsoff0 + (qi << 4) * 32;
            gload_lds16(Ah + (size_t)(m0 + row) * lda + kt + scol, &sA[0][lo]);
            gload_lds16(Bh + (size_t)(n0 + row) * ldb + kt + scol, &sB[0][lo]);
            if constexpr (SPLIT) {
                gload_lds16(Al + (size_t)(m0 + row) * lda + kt + scol, &sA[1][lo]);
                gload_lds16(Bl + (size_t)(n0 + row) * ldb + kt + scol, &sB[1][lo]);
            }
        }
        __syncthreads();   // drains vmcnt -> tiles resident

        short8 aH[4], bH[4];
        #pragma unroll
        for (int i = 0; i < 4; ++i)
            aH[i] = *(const short8*)&sA[0][(wm + i * 16 + fr) * 32 + ((fq ^ (fr & 3)) << 3)];
        #pragma unroll
        for (int j = 0; j < 4; ++j)
            bH[j] = *(const short8*)&sB[0][(wn + j * 16 + fr) * 32 + ((fq ^ (fr & 3)) << 3)];
        #pragma unroll
        for (int i = 0; i < 4; ++i)
            #pragma unroll
            for (int j = 0; j < 4; ++j)
                acc[i][j] = __builtin_amdgcn_mfma_f32_16x16x32_bf16(aH[i], bH[j], acc[i][j], 0, 0, 0);
        if constexpr (SPLIT) {
            short8 aL[4], bL[4];
            #pragma unroll
            for (int i = 0; i < 4; ++i)
                aL[i] = *(const short8*)&sA[1][(wm + i * 16 + fr) * 32 + ((fq ^ (fr & 3)) << 3)];
            #pragma unroll
            for (int j = 0; j < 4; ++j)
                bL[j] = *(const short8*)&sB[1][(wn + j * 16 + fr) * 32 + ((fq ^ (fr & 3)) << 3)];
            #pragma unroll
            for (int i = 0; i < 4; ++i)
                #pragma unroll
                for (int j = 0; j < 4; ++j) {
                    acc[i][j] = __builtin_amdgcn_mfma_f32_16x16x32_bf16(aL[i], bH[j], acc[i][j], 0, 0, 0);
                    acc[i][j] = __builtin_amdgcn_mfma_f32_16x16x32_bf16(aH[i], bL[j], acc[i][j], 0, 0, 0);
                }
        }
    }
    // C/D layout: col = lane&15, row = (lane>>4)*4 + reg
    #pragma unroll
    for (int i = 0; i < 4; ++i)
        #pragma unroll
        for (int j = 0; j < 4; ++j) {
            int m = m0 + wm + i * 16 + fq * 4;
            int n = n0 + wn + j * 16 + fr;
            #pragma unroll
            for (int r = 0; r < 4; ++r)
                C[(size_t)(m + r) * ldc + n] = acc[i][j][r];
        }
}

// ---------------- launch ----------------
extern "C" void kernel_launch(void* const* d_in, const int* in_sizes, int n_in,
                              void* d_out, int out_size, void* d_ws, size_t ws_size,
                              hipStream_t stream) {
    const int*   ids   = (const int*)d_in[0];
    const float* emb   = (const float*)d_in[1];
    const float* W_in  = (const float*)d_in[2];
    const float* cw    = (const float*)d_in[3];
    const float* cb    = (const float*)d_in[4];
    const float* W_x   = (const float*)d_in[5];
    const float* W_dt  = (const float*)d_in[6];
    const float* b_dt  = (const float*)d_in[7];
    const float* Alog  = (const float*)d_in[8];
    const float* Dp    = (const float*)d_in[9];
    const float* W_out = (const float*)d_in[10];
    const float* ln_g  = (const float*)d_in[11];
    const float* ln_b  = (const float*)d_in[12];
    const float* W_hd  = (const float*)d_in[13];

    char* ws = (char*)d_ws;
    float* xb   = (float*)(ws + 0);            // 4096x768   f32
    float* xz   = (float*)(ws + 12582912);     // 4096x3072  f32 (reused: dtp, u, head bf16)
    float* ssm  = (float*)(ws + 62914560);     // 4096x1536  f32
    float* szb  = (float*)(ws + 88080384);     // 4096x1536  f32
    float* dbl  = (float*)(ws + 113246208);    // 4096x80    f32
    u16*   Ahb  = (u16*)(ws + 114556928);      // 4096x1536  bf16
    u16*   Alb  = (u16*)(ws + 127139840);
    u16*   Bhb  = (u16*)(ws + 139722752);      // 3072x768   bf16
    u16*   Blb  = (u16*)(ws + 144441344);
    u16*   dblh = (u16*)(ws + 149159936);      // 4096x80    bf16
    u16*   dbll = (u16*)(ws + 149815296);      // total 150,470,656 B

    float* dtp = xz;                           // xz region dead after conv
    float* ub  = xz + (size_t)NROWS * DINNER;
    u16*   lnh = Ahb;                          // reuse after last layer
    u16*   hdh = (u16*)xz;                     // 32000x768 bf16 = 49.15MB <= xz region

    // scan scratch: Ahb/Alb/Bhb regions are dead between dt_proj gemm and out_proj split
    float* hendb = (float*)Ahb;                // 6,291,456 B (fits 12.58MB)
    float* Pb    = (float*)Alb;
    float* h0b   = (float*)Bhb;

    k_embed<<<NROWS, 256, 0, stream>>>(ids, emb, xb);

    for (int i = 0; i < 4; ++i) {
        // in_proj: xz = x @ W_in^T   (M=4096,N=3072,K=768) -- fast path
        k_split<<<2048, 256, 0, stream>>>(xb, Ahb, Alb, NROWS * DMODEL / 4);
        k_split<<<2048, 256, 0, stream>>>(W_in + (size_t)i * 3072 * DMODEL, Bhb, Blb, 3072 * DMODEL / 4);
        k_gemm_fast<1><<<dim3(24, 32), 256, 0, stream>>>(Ahb, Alb, Bhb, Blb, xz,
                                                         DMODEL, DMODEL, 3072, DMODEL);
        // conv + silu, silu(z)
        k_conv_silu<<<dim3(6, NROWS), 256, 0, stream>>>(xz, cw + (size_t)i * DINNER * 4,
                                                        cb + (size_t)i * DINNER, ssm, szb);
        // x_proj: dbl = ssm @ W_x^T  (N=80,K=1536) -- generic (N not /128)
        k_split<<<2048, 256, 0, stream>>>(ssm, Ahb, Alb, NROWS * DINNER / 4);
        k_split<<<480, 256, 0, stream>>>(W_x + (size_t)i * DXP * DINNER, Bhb, Blb, DXP * DINNER / 4);
        k_gemm<1><<<dim3(1, 32), 256, 0, stream>>>(Ahb, Alb, Bhb, Blb, dbl,
                                                   NROWS, DXP, DINNER, DINNER, DINNER, DXP);
        // dt_proj: dtp = dbl[:, :48] @ W_dt^T  (N=1536,K=48, lda=80) -- generic (K not /32)
        k_split<<<320, 256, 0, stream>>>(dbl, dblh, dbll, NROWS * DXP / 4);
        k_split<<<72, 256, 0, stream>>>(W_dt + (size_t)i * DINNER * DTRANK, Bhb, Blb, DINNER * DTRANK / 4);
        k_gemm<1><<<dim3(12, 32), 256, 0, stream>>>(dblh, dbll, Bhb, Blb, dtp,
                                                    NROWS, DINNER, DTRANK, DXP, DTRANK, DINNER);
        // selective scan, chunk-parallel
        k_softplus<<<2048, 256, 0, stream>>>(dtp, b_dt + (size_t)i * DINNER, NROWS * DINNER / 4);
        k_scan1<<<dim3(NCHUNK, 2 * (DINNER / 16)), 256, 0, stream>>>(
            dtp, ssm, dbl, Alog + (size_t)i * DINNER * DSTATE, hendb, Pb);
        k_scan2<<<192, 256, 0, stream>>>(hendb, Pb, h0b);
        k_scan3<<<dim3(NCHUNK, 2 * (DINNER / 16)), 256, 0, stream>>>(
            dtp, ssm, dbl, Alog + (size_t)i * DINNER * DSTATE,
            Dp + (size_t)i * DINNER, szb, h0b, ub);
        // out_proj: x = u @ W_out^T  (N=768,K=1536) -- fast path
        k_split<<<2048, 256, 0, stream>>>(ub, Ahb, Alb, NROWS * DINNER / 4);
        k_split<<<2048, 256, 0, stream>>>(W_out + (size_t)i * DMODEL * DINNER, Bhb, Blb, DMODEL * DINNER / 4);
        k_gemm_fast<1><<<dim3(6, 32), 256, 0, stream>>>(Ahb, Alb, Bhb, Blb, xb,
                                                        DINNER, DINNER, DMODEL, DINNER);
    }

    k_ln<<<NROWS, 256, 0, stream>>>(xb, ln_g, ln_b, lnh);
    k_split<<<8192, 256, 0, stream>>>(W_hd, hdh, (u16*)nullptr, NVOCAB * DMODEL / 4);
    // head: logits = ln(x) @ W_head^T  (M=4096,N=32000,K=768) -- fast path, plain bf16
    k_gemm_fast<0><<<dim3(250, 32), 256, 0, stream>>>(lnh, nullptr, hdh, nullptr, (float*)d_out,
                                                      DMODEL, DMODEL, NVOCAB, DMODEL);
}

// Round 3
// 2662.982 us; speedup vs baseline: 3.4993x; 1.0944x over previous
//
#include <hip/hip_runtime.h>
#include <hip/hip_bf16.h>

// ---------------- problem constants ----------------
#define DMODEL 768
#define DINNER 1536
#define NROWS  4096      // B*L
#define SEQLEN 2048
#define DSTATE 16
#define DTRANK 48
#define DXP    80        // DTRANK + 2*DSTATE
#define NVOCAB 32000
#define TCHUNK 64
#define NCHUNK 32        // SEQLEN / TCHUNK
#define KSPLIT 8         // x_proj split-K factor

typedef unsigned short u16;
typedef __attribute__((ext_vector_type(8))) short  short8;
typedef __attribute__((ext_vector_type(4))) float  floatx4;

__device__ __forceinline__ u16 f2bf(float f) {
    unsigned u = __builtin_bit_cast(unsigned, f);
    unsigned r = 0x7FFFu + ((u >> 16) & 1u);   // RNE
    return (u16)((u + r) >> 16);
}
__device__ __forceinline__ float bf2f(u16 h) {
    unsigned u = ((unsigned)h) << 16;
    return __builtin_bit_cast(float, u);
}
__device__ __forceinline__ float siluf(float x) { return x / (1.f + expf(-x)); }
__device__ __forceinline__ float softplusf(float x) {
    return fmaxf(x, 0.f) + log1pf(__expf(-fabsf(x)));
}
// async global -> LDS, 16B per lane; l must be wave-uniform
__device__ __forceinline__ void gload_lds16(const u16* g, u16* l) {
    __builtin_amdgcn_global_load_lds((const __attribute__((address_space(1))) void*)g,
                                     (__attribute__((address_space(3))) void*)l, 16, 0, 0);
}

// ---------------- split fp32 -> bf16 hi/lo (weights only now) ----------------
__global__ void k_split(const float* __restrict__ in, u16* __restrict__ hi,
                        u16* __restrict__ lo, int n4) {
    int i = blockIdx.x * blockDim.x + threadIdx.x;
    int stride = gridDim.x * blockDim.x;
    for (; i < n4; i += stride) {
        float4 f = ((const float4*)in)[i];
        u16 h0 = f2bf(f.x), h1 = f2bf(f.y), h2 = f2bf(f.z), h3 = f2bf(f.w);
        ushort4 hv; hv.x = h0; hv.y = h1; hv.z = h2; hv.w = h3;
        ((ushort4*)hi)[i] = hv;
        if (lo) {
            ushort4 lv;
            lv.x = f2bf(f.x - bf2f(h0));
            lv.y = f2bf(f.y - bf2f(h1));
            lv.z = f2bf(f.z - bf2f(h2));
            lv.w = f2bf(f.w - bf2f(h3));
            ((ushort4*)lo)[i] = lv;
        }
    }
}

// ---------------- embedding gather + fused split ----------------
__global__ void k_embed(const int* __restrict__ ids, const float* __restrict__ emb,
                        float* __restrict__ x, u16* __restrict__ xh, u16* __restrict__ xl) {
    int row = blockIdx.x;
    int id = ids[row];
    const float* src = emb + (size_t)id * DMODEL;
    float* dst = x + (size_t)row * DMODEL;
    u16* dh = xh + (size_t)row * DMODEL;
    u16* dl = xl + (size_t)row * DMODEL;
    for (int c = threadIdx.x; c < DMODEL; c += blockDim.x) {
        float v = src[c];
        dst[c] = v;
        u16 h = f2bf(v);
        dh[c] = h;
        dl[c] = f2bf(v - bf2f(h));
    }
}

// ---------------- causal conv(k=4) + silu -> ssm hi/lo, plus silu(z) f32 ----------------
__global__ void k_conv_silu(const float* __restrict__ xz, const float* __restrict__ cw,
                            const float* __restrict__ cb, u16* __restrict__ ssmh,
                            u16* __restrict__ ssml, float* __restrict__ sz) {
    int row = blockIdx.y;                                  // 0..4095
    int d   = blockIdx.x * blockDim.x + threadIdx.x;       // 0..1535
    int t   = row & (SEQLEN - 1);
    float acc = cb[d];
    #pragma unroll
    for (int k = 0; k < 4; ++k) {
        int tt = t + k - 3;
        if (tt >= 0) acc += xz[(size_t)(row + k - 3) * (2 * DINNER) + d] * cw[d * 4 + k];
    }
    float s = siluf(acc);
    u16 h = f2bf(s);
    size_t o = (size_t)row * DINNER + d;
    ssmh[o] = h;
    ssml[o] = f2bf(s - bf2f(h));
    float z = xz[(size_t)row * (2 * DINNER) + DINNER + d];
    sz[o] = siluf(z);
}

// ---------------- chunked selective scan ----------------
// phase 1: per-chunk local scan (h0 = 0), record final h and P = prod(dA)
__global__ void k_scan1(const float* __restrict__ dtp, const u16* __restrict__ ssmh,
                        const u16* __restrict__ ssml, const float* __restrict__ dbl,
                        const float* __restrict__ Alog,
                        float* __restrict__ hend, float* __restrict__ Pout) {
    int ch   = blockIdx.x;
    int b    = blockIdx.y / (DINNER / 16);
    int dblk = blockIdx.y % (DINNER / 16);
    int dl = threadIdx.x >> 4;
    int s  = threadIdx.x & 15;
    int d  = dblk * 16 + dl;
    float A = -__expf(Alog[d * DSTATE + s]);
    float h = 0.f, P = 1.f;
    size_t row = (size_t)b * SEQLEN + (size_t)ch * TCHUNK;
    for (int t = 0; t < TCHUNK; ++t, ++row) {
        float dt = dtp[row * DINNER + d];
        float xv = bf2f(ssmh[row * DINNER + d]) + bf2f(ssml[row * DINNER + d]);
        float Bv = dbl[row * DXP + DTRANK + s];
        float dA = __expf(dt * A);
        h = h * dA + dt * xv * Bv;
        P *= dA;
    }
    size_t o = (((size_t)b * NCHUNK + ch) * DINNER + d) * DSTATE + s;
    hend[o] = h;
    Pout[o] = P;
}

// phase 2: stitch chunk boundaries: h0[c+1] = hend[c] + P[c]*h0[c]
__global__ void k_scan2(const float* __restrict__ hend, const float* __restrict__ P,
                        float* __restrict__ h0) {
    int idx = blockIdx.x * blockDim.x + threadIdx.x;   // b*DINNER*DSTATE + d*DSTATE + s
    int b  = idx / (DINNER * DSTATE);
    int ds = idx % (DINNER * DSTATE);
    float h = 0.f;
    size_t base = (size_t)b * NCHUNK * DINNER * DSTATE + ds;
    for (int c = 0; c < NCHUNK; ++c) {
        size_t o = base + (size_t)c * (DINNER * DSTATE);
        h0[o] = h;
        h = hend[o] + P[o] * h;
    }
}

// phase 3: re-scan each chunk from correct h0, emit u as bf16 hi/lo
__global__ void k_scan3(const float* __restrict__ dtp, const u16* __restrict__ ssmh,
                        const u16* __restrict__ ssml, const float* __restrict__ dbl,
                        const float* __restrict__ Alog, const float* __restrict__ Dpv,
                        const float* __restrict__ sz, const float* __restrict__ h0,
                        u16* __restrict__ uh, u16* __restrict__ ul) {
    int ch   = blockIdx.x;
    int b    = blockIdx.y / (DINNER / 16);
    int dblk = blockIdx.y % (DINNER / 16);
    int dl = threadIdx.x >> 4;
    int s  = threadIdx.x & 15;
    int d  = dblk * 16 + dl;
    float A  = -__expf(Alog[d * DSTATE + s]);
    float Dd = Dpv[d];
    float h  = h0[(((size_t)b * NCHUNK + ch) * DINNER + d) * DSTATE + s];
    size_t row = (size_t)b * SEQLEN + (size_t)ch * TCHUNK;
    for (int t = 0; t < TCHUNK; ++t, ++row) {
        float dt = dtp[row * DINNER + d];
        float xv = bf2f(ssmh[row * DINNER + d]) + bf2f(ssml[row * DINNER + d]);
        float Bv = dbl[row * DXP + DTRANK + s];
        float Cv = dbl[row * DXP + DTRANK + DSTATE + s];
        float dA = __expf(dt * A);
        h = h * dA + dt * xv * Bv;
        float yv = h * Cv;
        yv += __shfl_xor(yv, 1);
        yv += __shfl_xor(yv, 2);
        yv += __shfl_xor(yv, 4);
        yv += __shfl_xor(yv, 8);
        if (s == 0) {
            float val = (yv + xv * Dd) * sz[row * DINNER + d];
            u16 hh = f2bf(val);
            uh[row * DINNER + d] = hh;
            ul[row * DINNER + d] = f2bf(val - bf2f(hh));
        }
    }
}

// ---------------- LayerNorm -> bf16 ----------------
__global__ void k_ln(const float* __restrict__ x, const float* __restrict__ g,
                     const float* __restrict__ bb, u16* __restrict__ out) {
    __shared__ float red[256];
    int row = blockIdx.x;
    int tid = threadIdx.x;
    const float* xr = x + (size_t)row * DMODEL;
    float v0 = xr[tid], v1 = xr[tid + 256], v2 = xr[tid + 512];
    red[tid] = v0 + v1 + v2;
    __syncthreads();
    for (int o = 128; o > 0; o >>= 1) { if (tid < o) red[tid] += red[tid + o]; __syncthreads(); }
    float mu = red[0] * (1.f / 768.f);
    __syncthreads();
    red[tid] = (v0 - mu) * (v0 - mu) + (v1 - mu) * (v1 - mu) + (v2 - mu) * (v2 - mu);
    __syncthreads();
    for (int o = 128; o > 0; o >>= 1) { if (tid < o) red[tid] += red[tid + o]; __syncthreads(); }
    float var = red[0] * (1.f / 768.f);
    float rs = rsqrtf(var + 1e-5f);
    u16* orow = out + (size_t)row * DMODEL;
    orow[tid]       = f2bf((v0 - mu) * rs * g[tid]       + bb[tid]);
    orow[tid + 256] = f2bf((v1 - mu) * rs * g[tid + 256] + bb[tid + 256]);
    orow[tid + 512] = f2bf((v2 - mu) * rs * g[tid + 512] + bb[tid + 512]);
}

// ---------------- generic MFMA GEMM (bounds-checked): C = A[M][K] * B[N][K]^T ----------------
// EPI==1: C = softplus(C + bias[n])  (dt_proj)
template<int SPLIT, int EPI>
__global__ __launch_bounds__(256, 2)
void k_gemm(const u16* __restrict__ Ah, const u16* __restrict__ Al,
            const u16* __restrict__ Bh, const u16* __restrict__ Bl,
            float* __restrict__ C, const float* __restrict__ bias,
            int M, int N, int K, int lda, int ldb, int ldc) {
    constexpr int LDK = 40;                       // 32 + 8 pad (80B row stride)
    __shared__ __align__(16) u16 sA[2][128 * LDK];
    __shared__ __align__(16) u16 sB[2][128 * LDK];
    const int tid  = threadIdx.x;
    const int m0 = blockIdx.y * 128, n0 = blockIdx.x * 128;
    const int wave = tid >> 6, lane = tid & 63;
    const int wm = (wave >> 1) * 64, wn = (wave & 1) * 64;
    const int fr = lane & 15, fq = lane >> 4;

    floatx4 acc[4][4];
    #pragma unroll
    for (int i = 0; i < 4; ++i)
        #pragma unroll
        for (int j = 0; j < 4; ++j)
            #pragma unroll
            for (int r = 0; r < 4; ++r) acc[i][j][r] = 0.f;

    for (int kt = 0; kt < K; kt += 32) {
        __syncthreads();
        #pragma unroll
        for (int half = 0; half < 2; ++half) {
            int c  = tid + half * 256;       // 0..511
            int rr = c >> 2;                 // tile row 0..127
            int ko = (c & 3) * 8;            // k offset in tile
            int gk = kt + ko;
            {   // A tile(s)
                int gm = m0 + rr;
                short8 vh = {0,0,0,0,0,0,0,0}, vl = {0,0,0,0,0,0,0,0};
                if (gm < M) {
                    const u16* p = Ah + (size_t)gm * lda + gk;
                    if (gk + 8 <= K) vh = *(const short8*)p;
                    else { for (int jj = 0; jj < 8; ++jj) if (gk + jj < K) vh[jj] = (short)p[jj]; }
                    if (SPLIT) {
                        const u16* q = Al + (size_t)gm * lda + gk;
                        if (gk + 8 <= K) vl = *(const short8*)q;
                        else { for (int jj = 0; jj < 8; ++jj) if (gk + jj < K) vl[jj] = (short)q[jj]; }
                    }
                }
                *(short8*)&sA[0][rr * LDK + ko] = vh;
                if (SPLIT) *(short8*)&sA[1][rr * LDK + ko] = vl;
            }
            {   // B tile(s)
                int gn = n0 + rr;
                short8 vh = {0,0,0,0,0,0,0,0}, vl = {0,0,0,0,0,0,0,0};
                if (gn < N) {
                    const u16* p = Bh + (size_t)gn * ldb + gk;
                    if (gk + 8 <= K) vh = *(const short8*)p;
                    else { for (int jj = 0; jj < 8; ++jj) if (gk + jj < K) vh[jj] = (short)p[jj]; }
                    if (SPLIT) {
                        const u16* q = Bl + (size_t)gn * ldb + gk;
                        if (gk + 8 <= K) vl = *(const short8*)q;
                        else { for (int jj = 0; jj < 8; ++jj) if (gk + jj < K) vl[jj] = (short)q[jj]; }
                    }
                }
                *(short8*)&sB[0][rr * LDK + ko] = vh;
                if (SPLIT) *(short8*)&sB[1][rr * LDK + ko] = vl;
            }
        }
        __syncthreads();

        short8 aH[4], bH[4];
        #pragma unroll
        for (int i = 0; i < 4; ++i) aH[i] = *(const short8*)&sA[0][(wm + i * 16 + fr) * LDK + fq * 8];
        #pragma unroll
        for (int j = 0; j < 4; ++j) bH[j] = *(const short8*)&sB[0][(wn + j * 16 + fr) * LDK + fq * 8];
        #pragma unroll
        for (int i = 0; i < 4; ++i)
            #pragma unroll
            for (int j = 0; j < 4; ++j)
                acc[i][j] = __builtin_amdgcn_mfma_f32_16x16x32_bf16(aH[i], bH[j], acc[i][j], 0, 0, 0);
        if (SPLIT) {
            short8 aL[4], bL[4];
            #pragma unroll
            for (int i = 0; i < 4; ++i) aL[i] = *(const short8*)&sA[1][(wm + i * 16 + fr) * LDK + fq * 8];
            #pragma unroll
            for (int j = 0; j < 4; ++j) bL[j] = *(const short8*)&sB[1][(wn + j * 16 + fr) * LDK + fq * 8];
            #pragma unroll
            for (int i = 0; i < 4; ++i)
                #pragma unroll
                for (int j = 0; j < 4; ++j) {
                    acc[i][j] = __builtin_amdgcn_mfma_f32_16x16x32_bf16(aL[i], bH[j], acc[i][j], 0, 0, 0);
                    acc[i][j] = __builtin_amdgcn_mfma_f32_16x16x32_bf16(aH[i], bL[j], acc[i][j], 0, 0, 0);
                }
        }
    }
    // C/D layout (verified m89/m91): col = lane&15, row = (lane>>4)*4 + reg
    #pragma unroll
    for (int i = 0; i < 4; ++i)
        #pragma unroll
        for (int j = 0; j < 4; ++j) {
            int m = m0 + wm + i * 16 + fq * 4;
            int n = n0 + wn + j * 16 + fr;
            if (n < N) {
                #pragma unroll
                for (int r = 0; r < 4; ++r)
                    if (m + r < M) {
                        float v = acc[i][j][r];
                        if (EPI) v = softplusf(v + bias[n]);
                        C[(size_t)(m + r) * ldc + n] = v;
                    }
            }
        }
}

// ---------------- fast MFMA GEMM: requires M%128==0, N%128==0, K%32==0 ----------------
// global_load_lds staging (linear LDS dest, pre-swizzled global source, swizzled read)
// EPI==1: additionally write bf16 hi/lo split of C to Ch/Cl (same ldc)
template<int SPLIT, int EPI>
__global__ __launch_bounds__(256, 2)
void k_gemm_fast(const u16* __restrict__ Ah, const u16* __restrict__ Al,
                 const u16* __restrict__ Bh, const u16* __restrict__ Bl,
                 float* __restrict__ C, u16* __restrict__ Ch, u16* __restrict__ Cl,
                 int lda, int ldb, int ldc, int K) {
    __shared__ __align__(16) u16 sA[SPLIT + 1][128 * 32];
    __shared__ __align__(16) u16 sB[SPLIT + 1][128 * 32];
    // bijective XCD swizzle (m204)
    const int nx = gridDim.x;
    const int nwg = nx * gridDim.y;
    const int lin = blockIdx.y * nx + blockIdx.x;
    const int qq = nwg >> 3, rr8 = nwg & 7;
    const int xcd = lin & 7, jj = lin >> 3;
    const int swz = (xcd < rr8 ? xcd * (qq + 1) : rr8 * (qq + 1) + (xcd - rr8) * qq) + jj;
    const int n0 = (swz % nx) * 128, m0 = (swz / nx) * 128;

    const int tid  = threadIdx.x;
    const int wave = tid >> 6, lane = tid & 63;
    const int wm = (wave >> 1) * 64, wn = (wave & 1) * 64;
    const int fr = lane & 15, fq = lane >> 4;

    // staging geometry: wave covers rows [wave*32, wave*32+32) in two 1KB issues
    const int srow = (wave << 5) + (lane >> 2);                   // row for qi=0
    const int scol = (((lane & 3) ^ ((lane >> 2) & 3)) << 3);     // pre-swizzled u16 col
    const int ldsoff0 = (wave << 5) * 32;                         // wave-uniform

    floatx4 acc[4][4];
    #pragma unroll
    for (int i = 0; i < 4; ++i)
        #pragma unroll
        for (int j = 0; j < 4; ++j)
            #pragma unroll
            for (int r = 0; r < 4; ++r) acc[i][j][r] = 0.f;

    for (int kt = 0; kt < K; kt += 32) {
        __syncthreads();
        #pragma unroll
        for (int qi = 0; qi < 2; ++qi) {
            const int row = srow + qi * 16;
            const int lo  = ldsoff0 + (qi << 4) * 32;
            gload_lds16(Ah + (size_t)(m0 + row) * lda + kt + scol, &sA[0][lo]);
            gload_lds16(Bh + (size_t)(n0 + row) * ldb + kt + scol, &sB[0][lo]);
            if constexpr (SPLIT) {
                gload_lds16(Al + (size_t)(m0 + row) * lda + kt + scol, &sA[1][lo]);
                gload_lds16(Bl + (size_t)(n0 + row) * ldb + kt + scol, &sB[1][lo]);
            }
        }
        __syncthreads();   // drains vmcnt -> tiles resident

        short8 aH[4], bH[4];
        #pragma unroll
        for (int i = 0; i < 4; ++i)
            aH[i] = *(const short8*)&sA[0][(wm + i * 16 + fr) * 32 + ((fq ^ (fr & 3)) << 3)];
        #pragma unroll
        for (int j = 0; j < 4; ++j)
            bH[j] = *(const short8*)&sB[0][(wn + j * 16 + fr) * 32 + ((fq ^ (fr & 3)) << 3)];
        #pragma unroll
        for (int i = 0; i < 4; ++i)
            #pragma unroll
            for (int j = 0; j < 4; ++j)
                acc[i][j] = __builtin_amdgcn_mfma_f32_16x16x32_bf16(aH[i], bH[j], acc[i][j], 0, 0, 0);
        if constexpr (SPLIT) {
            short8 aL[4], bL[4];
            #pragma unroll
            for (int i = 0; i < 4; ++i)
                aL[i] = *(const short8*)&sA[1][(wm + i * 16 + fr) * 32 + ((fq ^ (fr & 3)) << 3)];
            #pragma unroll
            for (int j = 0; j < 4; ++j)
                bL[j] = *(const short8*)&sB[1][(wn + j * 16 + fr) * 32 + ((fq ^ (fr & 3)) << 3)];
            #pragma unroll
            for (int i = 0; i < 4; ++i)
                #pragma unroll
                for (int j = 0; j < 4; ++j) {
                    acc[i][j] = __builtin_amdgcn_mfma_f32_16x16x32_bf16(aL[i], bH[j], acc[i][j], 0, 0, 0);
                    acc[i][j] = __builtin_amdgcn_mfma_f32_16x16x32_bf16(aH[i], bL[j], acc[i][j], 0, 0, 0);
                }
        }
    }
    // C/D layout: col = lane&15, row = (lane>>4)*4 + reg
    #pragma unroll
    for (int i = 0; i < 4; ++i)
        #pragma unroll
        for (int j = 0; j < 4; ++j) {
            int m = m0 + wm + i * 16 + fq * 4;
            int n = n0 + wn + j * 16 + fr;
            #pragma unroll
            for (int r = 0; r < 4; ++r) {
                float v = acc[i][j][r];
                C[(size_t)(m + r) * ldc + n] = v;
                if constexpr (EPI) {
                    u16 h = f2bf(v);
                    Ch[(size_t)(m + r) * ldc + n] = h;
                    Cl[(size_t)(m + r) * ldc + n] = f2bf(v - bf2f(h));
                }
            }
        }
}

// ---------------- x_proj split-K: part[ks] = ssm[128-tile] @ W_x^T (K chunk) ----------------
// BM=128, BN=80 (5x16), K/KSPLIT=192 per block. B rows 80..127 staged but never read.
__global__ __launch_bounds__(256, 2)
void k_xproj(const u16* __restrict__ Ah, const u16* __restrict__ Al,
             const u16* __restrict__ Bh, const u16* __restrict__ Bl,
             float* __restrict__ part) {
    __shared__ __align__(16) u16 sA[2][128 * 32];
    __shared__ __align__(16) u16 sB[2][128 * 32];
    const int ks = blockIdx.x;                 // 0..KSPLIT-1
    const int m0 = blockIdx.y * 128;
    const int k0 = ks * (DINNER / KSPLIT);     // 192
    const int tid  = threadIdx.x;
    const int wave = tid >> 6, lane = tid & 63;
    const int wm = wave * 32;                  // wave owns 32 rows x 80 cols
    const int fr = lane & 15, fq = lane >> 4;
    const int srow = (wave << 5) + (lane >> 2);
    const int scol = (((lane & 3) ^ ((lane >> 2) & 3)) << 3);
    const int ldsoff0 = (wave << 5) * 32;

    floatx4 acc[2][5];
    #pragma unroll
    for (int i = 0; i < 2; ++i)
        #pragma unroll
        for (int j = 0; j < 5; ++j)
            #pragma unroll
            for (int r = 0; r < 4; ++r) acc[i][j][r] = 0.f;

    for (int kt = 0; kt < DINNER / KSPLIT; kt += 32) {
        __syncthreads();
        #pragma unroll
        for (int qi = 0; qi < 2; ++qi) {
            const int row = srow + qi * 16;
            const int lo  = ldsoff0 + (qi << 4) * 32;
            gload_lds16(Ah + (size_t)(m0 + row) * DINNER + k0 + kt + scol, &sA[0][lo]);
            gload_lds16(Al + (size_t)(m0 + row) * DINNER + k0 + kt + scol, &sA[1][lo]);
            gload_lds16(Bh + (size_t)row * DINNER + k0 + kt + scol, &sB[0][lo]);
            gload_lds16(Bl + (size_t)row * DINNER + k0 + kt + scol, &sB[1][lo]);
        }
        __syncthreads();

        short8 aH[2], aL[2], bH[5], bL[5];
        #pragma unroll
        for (int i = 0; i < 2; ++i) {
            aH[i] = *(const short8*)&sA[0][(wm + i * 16 + fr) * 32 + ((fq ^ (fr & 3)) << 3)];
            aL[i] = *(const short8*)&sA[1][(wm + i * 16 + fr) * 32 + ((fq ^ (fr & 3)) << 3)];
        }
        #pragma unroll
        for (int j = 0; j < 5; ++j) {
            bH[j] = *(const short8*)&sB[0][(j * 16 + fr) * 32 + ((fq ^ (fr & 3)) << 3)];
            bL[j] = *(const short8*)&sB[1][(j * 16 + fr) * 32 + ((fq ^ (fr & 3)) << 3)];
        }
        #pragma unroll
        for (int i = 0; i < 2; ++i)
            #pragma unroll
            for (int j = 0; j < 5; ++j) {
                acc[i][j] = __builtin_amdgcn_mfma_f32_16x16x32_bf16(aH[i], bH[j], acc[i][j], 0, 0, 0);
                acc[i][j] = __builtin_amdgcn_mfma_f32_16x16x32_bf16(aL[i], bH[j], acc[i][j], 0, 0, 0);
                acc[i][j] = __builtin_amdgcn_mfma_f32_16x16x32_bf16(aH[i], bL[j], acc[i][j], 0, 0, 0);
            }
    }
    // partial store: part[((ks*NROWS + m) * 80) + n]
    #pragma unroll
    for (int i = 0; i < 2; ++i)
        #pragma unroll
        for (int j = 0; j < 5; ++j) {
            int m = m0 + wm + i * 16 + fq * 4;
            int n = j * 16 + fr;
            #pragma unroll
            for (int r = 0; r < 4; ++r)
                part[((size_t)ks * NROWS + m + r) * DXP + n] = acc[i][j][r];
        }
}

// reduce partials -> dbl f32 + bf16 hi/lo
__global__ void k_xreduce(const float* __restrict__ part, float* __restrict__ dbl,
                          u16* __restrict__ dh, u16* __restrict__ dl) {
    int i = blockIdx.x * blockDim.x + threadIdx.x;   // float4 index, NROWS*80/4 total
    float4 s = ((const float4*)part)[i];
    #pragma unroll
    for (int ks = 1; ks < KSPLIT; ++ks) {
        float4 p = ((const float4*)(part + (size_t)ks * NROWS * DXP))[i];
        s.x += p.x; s.y += p.y; s.z += p.z; s.w += p.w;
    }
    ((float4*)dbl)[i] = s;
    u16 h0 = f2bf(s.x), h1 = f2bf(s.y), h2 = f2bf(s.z), h3 = f2bf(s.w);
    ushort4 hv; hv.x = h0; hv.y = h1; hv.z = h2; hv.w = h3;
    ushort4 lv;
    lv.x = f2bf(s.x - bf2f(h0));
    lv.y = f2bf(s.y - bf2f(h1));
    lv.z = f2bf(s.z - bf2f(h2));
    lv.w = f2bf(s.w - bf2f(h3));
    ((ushort4*)dh)[i] = hv;
    ((ushort4*)dl)[i] = lv;
}

// ---------------- launch ----------------
extern "C" void kernel_launch(void* const* d_in, const int* in_sizes, int n_in,
                              void* d_out, int out_size, void* d_ws, size_t ws_size,
                              hipStream_t stream) {
    const int*   ids   = (const int*)d_in[0];
    const float* emb   = (const float*)d_in[1];
    const float* W_in  = (const float*)d_in[2];
    const float* cw    = (const float*)d_in[3];
    const float* cb    = (const float*)d_in[4];
    const float* W_x   = (const float*)d_in[5];
    const float* W_dt  = (const float*)d_in[6];
    const float* b_dt  = (const float*)d_in[7];
    const float* Alog  = (const float*)d_in[8];
    const float* Dp    = (const float*)d_in[9];
    const float* W_out = (const float*)d_in[10];
    const float* ln_g  = (const float*)d_in[11];
    const float* ln_b  = (const float*)d_in[12];
    const float* W_hd  = (const float*)d_in[13];

    char* ws = (char*)d_ws;
    float* xb    = (float*)(ws + 0);             // 4096x768  f32        [0, 12.58M)
    float* xz    = (float*)(ws + 12582912);      // 4096x3072 f32        [12.58M, 62.91M)
    float* szb   = (float*)(ws + 62914560);      // 4096x1536 f32        [62.91M, 88.08M)
    u16*   ssmh  = (u16*)(ws + 88080384);        // 4096x1536 bf16       [88.08M, 100.66M)
    u16*   ssml  = (u16*)(ws + 100663296);       //                      [100.66M, 113.25M)
    u16*   xAh   = (u16*)(ws + 113246208);       // 4096x768  bf16       [113.25M, 119.54M)
    u16*   xAl   = (u16*)(ws + 119537664);       //                      [119.54M, 125.83M)
    u16*   Bhb   = (u16*)(ws + 125829120);       // <=3072x768 bf16      [125.83M, 130.55M)
    u16*   Blb   = (u16*)(ws + 130547712);       //                      [130.55M, 135.27M)
    u16*   Wxh   = (u16*)(ws + 135266304);       // 80x1536 bf16         [135.27M, 135.51M)
    u16*   Wxl   = (u16*)(ws + 135512064);       //                      [135.51M, 135.76M)
    float* dbl   = (float*)(ws + 135757824);     // 4096x80  f32         [135.76M, 137.07M)
    u16*   dblh  = (u16*)(ws + 137068544);       // 4096x80  bf16
    u16*   dbll  = (u16*)(ws + 137723904);       //
    float* xpart = (float*)(ws + 138379264);     // 8x4096x80 f32        [138.38M, 148.87M)

    // xz region overlays (xz dead after conv):
    float* dtp = xz;                             // 4096x1536 f32 (25.17M)
    u16*   uhb = (u16*)(ws + 37748736);          // 4096x1536 bf16 (12.58M)
    u16*   ulb = (u16*)(ws + 50331648);          // 4096x1536 bf16 (12.58M)
    // scan scratch overlays (dead regions during scan):
    float* hendb = xpart;                        // 6.29M <= 10.49M
    float* Pb    = (float*)Bhb;                  // 6.29M <= Bhb+Blb (9.44M)
    float* h0b   = (float*)xAh;                  // 6.29M <= xAh+xAl (12.58M)
    // head overlays:
    u16* lnh = ssmh;                             // 6.29M <= 12.58M
    u16* hdh = (u16*)xz;                         // 49.15M <= 50.33M

    k_embed<<<NROWS, 256, 0, stream>>>(ids, emb, xb, xAh, xAl);

    for (int i = 0; i < 4; ++i) {
        // in_proj: xz = x @ W_in^T   (M=4096,N=3072,K=768)
        k_split<<<2048, 256, 0, stream>>>(W_in + (size_t)i * 3072 * DMODEL, Bhb, Blb, 3072 * DMODEL / 4);
        k_gemm_fast<1, 0><<<dim3(24, 32), 256, 0, stream>>>(xAh, xAl, Bhb, Blb, xz, nullptr, nullptr,
                                                            DMODEL, DMODEL, 3072, DMODEL);
        // conv + silu -> ssm hi/lo, silu(z) f32
        k_conv_silu<<<dim3(6, NROWS), 256, 0, stream>>>(xz, cw + (size_t)i * DINNER * 4,
                                                        cb + (size_t)i * DINNER, ssmh, ssml, szb);
        // x_proj: dbl = ssm @ W_x^T  (N=80,K=1536) -- split-K + reduce(fused split)
        k_split<<<120, 256, 0, stream>>>(W_x + (size_t)i * DXP * DINNER, Wxh, Wxl, DXP * DINNER / 4);
        k_xproj<<<dim3(KSPLIT, 32), 256, 0, stream>>>(ssmh, ssml, Wxh, Wxl, xpart);
        k_xreduce<<<320, 256, 0, stream>>>(xpart, dbl, dblh, dbll);
        // dt_proj: dtp = softplus(dbl[:, :48] @ W_dt^T + b_dt)  (N=1536,K=48, lda=80)
        k_split<<<72, 256, 0, stream>>>(W_dt + (size_t)i * DINNER * DTRANK, Bhb, Blb, DINNER * DTRANK / 4);
        k_gemm<1, 1><<<dim3(12, 32), 256, 0, stream>>>(dblh, dbll, Bhb, Blb, dtp,
                                                       b_dt + (size_t)i * DINNER,
                                                       NROWS, DINNER, DTRANK, DXP, DTRANK, DINNER);
        // chunk-parallel selective scan
        k_scan1<<<dim3(NCHUNK, 2 * (DINNER / 16)), 256, 0, stream>>>(
            dtp, ssmh, ssml, dbl, Alog + (size_t)i * DINNER * DSTATE, hendb, Pb);
        k_scan2<<<192, 256, 0, stream>>>(hendb, Pb, h0b);
        k_scan3<<<dim3(NCHUNK, 2 * (DINNER / 16)), 256, 0, stream>>>(
            dtp, ssmh, ssml, dbl, Alog + (size_t)i * DINNER * DSTATE,
            Dp + (size_t)i * DINNER, szb, h0b, uhb, ulb);
        // out_proj: x = u @ W_out^T  (N=768,K=1536), epilogue also splits xb -> xAh/xAl
        k_split<<<1152, 256, 0, stream>>>(W_out + (size_t)i * DMODEL * DINNER, Bhb, Blb, DMODEL * DINNER / 4);
        k_gemm_fast<1, 1><<<dim3(6, 32), 256, 0, stream>>>(uhb, ulb, Bhb, Blb, xb, xAh, xAl,
                                                           DINNER, DINNER, DMODEL, DINNER);
    }

    k_ln<<<NROWS, 256, 0, stream>>>(xb, ln_g, ln_b, lnh);
    k_split<<<8192, 256, 0, stream>>>(W_hd, hdh, (u16*)nullptr, NVOCAB * DMODEL / 4);
    // head: logits = ln(x) @ W_head^T  (M=4096,N=32000,K=768), plain bf16
    k_gemm_fast<0, 0><<<dim3(250, 32), 256, 0, stream>>>(lnh, nullptr, hdh, nullptr, (float*)d_out,
                                                         nullptr, nullptr,
                                                         DMODEL, DMODEL, NVOCAB, DMODEL);
}